// Round 6
// baseline (1010.053 us; speedup 1.0000x reference)
//
#include <hip/hip_runtime.h>

// Causal self-attention fwd, B=2, H=16, S=2048, D=64.
// d_out = [out (B*H*S*D)] ++ [attention (B*H*S*S)], both fp32.
//
// Round 6: MFMA. Round-5 counters: VALUBusy 55.8% with MfmaUtil 0.0 -- the
// vector pipe is the wall (fp32-FMA floor ~170-230 us) while the matrix pipe
// idles. This round moves QK^T and PV onto v_mfma_f32_16x16x32_bf16 with
// split-bf16 3-term products (x=hi+lo; x*y ~= hh+hl+lh, rel err ~2^-17 ->
// fp32-grade numerics). A pre-kernel converts Q,K -> bf16 hi/lo (row-major)
// and V -> bf16 hi/lo TRANSPOSED [bh][d][s] into d_ws, so every MFMA
// fragment is a direct 16B per-lane load. Skeleton unchanged from round 5:
// QB=8 rows/block, NT=256, score/e rows in LDS (64 KB, 2 blocks/CU),
// same softmax + att-write phases. M=16 tiles duplicate rows 8-15 (discarded).
// sE uses an XOR-octet swizzle (T2) so PV A-frag reads (16 lanes at 8KB row
// stride) are <=4-way instead of 16-way conflicted.
// Fallback: if ws_size < 50.3 MB, launch the round-5 VALU kernel unchanged.

#define B_ 2
#define H_ 16
#define S_ 2048
#define D_ 64
#define QB 8
#define NT 256
#define ELEMS (B_ * H_ * S_ * D_)                  // 4194304
#define WS_NEEDED (6ull * ELEMS * 2ull)            // 50331648 B

typedef unsigned short u16;
typedef unsigned int   u32;
typedef float f32x4 __attribute__((ext_vector_type(4)));
typedef short bf16x8 __attribute__((ext_vector_type(8)));

#define MFMA(a, b, c) __builtin_amdgcn_mfma_f32_16x16x32_bf16((a), (b), (c), 0, 0, 0)
// sE swizzle: octet index XORed with row (r in 0..7) -> spreads the 8KB row
// stride across banks for PV A-frag reads; quads stay contiguous.
#define EIDX(r, j) (((r) << 11) + ((((j) >> 3) ^ (r)) << 3) + ((j) & 7))

__device__ __forceinline__ float bf2f(u16 h) {
    union { u32 u; float f; } x; x.u = ((u32)h) << 16; return x.f;
}
__device__ __forceinline__ u16 f2bf_rne(float f) {
    u32 u = __float_as_uint(f);
    return (u16)((u + 0x7FFFu + ((u >> 16) & 1u)) >> 16);
}
__device__ __forceinline__ float wred_max(float v) {
    #pragma unroll
    for (int o = 32; o > 0; o >>= 1) v = fmaxf(v, __shfl_xor(v, o, 64));
    return v;
}
__device__ __forceinline__ float wred_sum(float v) {
    #pragma unroll
    for (int o = 32; o > 0; o >>= 1) v += __shfl_xor(v, o, 64);
    return v;
}
__device__ __forceinline__ bool sniff_f32(const void* Qv, int lane) {
    u32 wv = ((const u32*)Qv)[lane];
    int e0 = (int)((wv >> 7)  & 0xFFu);
    int e1 = (int)((wv >> 23) & 0xFFu);
    unsigned long long b = __ballot(e0 >= 0x8F || e1 >= 0x8F);
    return (__popcll(b) >= 4);
}

// ---------------- pre-kernel: fp32 -> bf16 hi/lo (+ V transpose) ----------------
__global__ __launch_bounds__(256)
void conv_kernel(const void* __restrict__ Qv, const void* __restrict__ Kv,
                 const void* __restrict__ Vv,
                 u16* __restrict__ qhi, u16* __restrict__ qlo,
                 u16* __restrict__ khi, u16* __restrict__ klo,
                 u16* __restrict__ vthi, u16* __restrict__ vtlo)
{
    __shared__ float sV[64][65];
    const int tid = threadIdx.x;
    const int blk = blockIdx.x;            // 1024 blocks: bh(32) x s-tile(32)
    const int bh  = blk >> 5;
    const int s0  = (blk & 31) << 6;
    const size_t base = (size_t)bh * S_ * D_;
    const bool isf32 = sniff_f32(Qv, tid & 63);

    const int sr = tid >> 2;               // 0..63 (s row in tile)
    const int dq = (tid & 3) << 4;         // 0,16,32,48
    const size_t roff = base + (size_t)(s0 + sr) * D_ + dq;

    float q16[16], k16[16], v16[16];
    if (isf32) {
        const float4* qp = (const float4*)((const float*)Qv + roff);
        const float4* kp = (const float4*)((const float*)Kv + roff);
        const float4* vp = (const float4*)((const float*)Vv + roff);
        #pragma unroll
        for (int i = 0; i < 4; ++i) {
            float4 a = qp[i]; q16[4*i+0]=a.x; q16[4*i+1]=a.y; q16[4*i+2]=a.z; q16[4*i+3]=a.w;
            float4 b = kp[i]; k16[4*i+0]=b.x; k16[4*i+1]=b.y; k16[4*i+2]=b.z; k16[4*i+3]=b.w;
            float4 c = vp[i]; v16[4*i+0]=c.x; v16[4*i+1]=c.y; v16[4*i+2]=c.z; v16[4*i+3]=c.w;
        }
    } else {
        const u16* qp = (const u16*)Qv + roff;
        const u16* kp = (const u16*)Kv + roff;
        const u16* vp = (const u16*)Vv + roff;
        #pragma unroll
        for (int i = 0; i < 16; ++i) { q16[i]=bf2f(qp[i]); k16[i]=bf2f(kp[i]); v16[i]=bf2f(vp[i]); }
    }

    alignas(16) u16 qh[16], ql[16], kh[16], kl[16];
    #pragma unroll
    for (int i = 0; i < 16; ++i) {
        u16 h = f2bf_rne(q16[i]); qh[i] = h; ql[i] = f2bf_rne(q16[i] - bf2f(h));
        h = f2bf_rne(k16[i]);     kh[i] = h; kl[i] = f2bf_rne(k16[i] - bf2f(h));
        sV[sr][dq + i] = v16[i];
    }
    *(bf16x8*)(qhi + roff)     = *(const bf16x8*)qh;
    *(bf16x8*)(qhi + roff + 8) = *(const bf16x8*)(qh + 8);
    *(bf16x8*)(qlo + roff)     = *(const bf16x8*)ql;
    *(bf16x8*)(qlo + roff + 8) = *(const bf16x8*)(ql + 8);
    *(bf16x8*)(khi + roff)     = *(const bf16x8*)kh;
    *(bf16x8*)(khi + roff + 8) = *(const bf16x8*)(kh + 8);
    *(bf16x8*)(klo + roff)     = *(const bf16x8*)kl;
    *(bf16x8*)(klo + roff + 8) = *(const bf16x8*)(kl + 8);
    __syncthreads();

    const int dr = tid >> 2;               // 0..63 (d row of Vt)
    const int sq = (tid & 3) << 4;
    alignas(16) u16 vh[16], vl[16];
    #pragma unroll
    for (int i = 0; i < 16; ++i) {
        float x = sV[sq + i][dr];
        u16 h = f2bf_rne(x); vh[i] = h; vl[i] = f2bf_rne(x - bf2f(h));
    }
    const size_t toff = base + (size_t)dr * S_ + s0 + sq;   // [bh][d][s]
    *(bf16x8*)(vthi + toff)     = *(const bf16x8*)vh;
    *(bf16x8*)(vthi + toff + 8) = *(const bf16x8*)(vh + 8);
    *(bf16x8*)(vtlo + toff)     = *(const bf16x8*)vl;
    *(bf16x8*)(vtlo + toff + 8) = *(const bf16x8*)(vl + 8);
}

// ---------------- main MFMA kernel ----------------
__global__ __launch_bounds__(NT)
void attn_mfma_kernel(const u16* __restrict__ qhi, const u16* __restrict__ qlo,
                      const u16* __restrict__ khi, const u16* __restrict__ klo,
                      const u16* __restrict__ vthi, const u16* __restrict__ vtlo,
                      const int* __restrict__ maskp,
                      float* __restrict__ out, float* __restrict__ att)
{
    const int tid  = threadIdx.x;
    const int lane = tid & 63;
    const int w    = tid >> 6;             // wave 0..3
    const int l15  = lane & 15;
    const int l4   = lane >> 4;

    const int bid0 = blockIdx.x;           // XCD swizzle, 8192 blocks
    const int bid  = (bid0 & 7) * 1024 + (bid0 >> 3);
    const int bh = bid >> 8;
    const int q0 = (bid & 255) << 3;
    const int causal = maskp[0];
    const int kmaxB = causal ? (q0 + QB - 1) : (S_ - 1);
    const int Tmax  = (kmaxB + 16) >> 4;   // 16-wide QK tiles
    const int Kc    = (kmaxB + 32) >> 5;   // 32-wide PV k-steps
    const int jWritten = Tmax << 4;
    const int jPV      = Kc << 5;

    __shared__ float sE[QB * S_];          // 64 KB, swizzled via EIDX
    __shared__ float sMaxP[4 * QB];
    __shared__ float sSumP[4 * QB];
    __shared__ float sM[QB];
    __shared__ float sInv[QB];

    const size_t base = (size_t)bh * S_ * D_;

    // ---- QK^T: C[m][j] tiles, A=Q (rows dup 8-15), B=K^T; 3-term split ----
    const u16* qrh = qhi + base + (size_t)(q0 + (l15 & 7)) * D_ + l4 * 8;
    const u16* qrl = qlo + base + (size_t)(q0 + (l15 & 7)) * D_ + l4 * 8;
    const bf16x8 ah0 = *(const bf16x8*)qrh;
    const bf16x8 ah1 = *(const bf16x8*)(qrh + 32);
    const bf16x8 al0 = *(const bf16x8*)qrl;
    const bf16x8 al1 = *(const bf16x8*)(qrl + 32);

    float rm[4] = {-INFINITY, -INFINITY, -INFINITY, -INFINITY};
    #pragma unroll 2
    for (int t = w; t < Tmax; t += 4) {
        const int j0 = t << 4;
        const u16* krh = khi + base + (size_t)(j0 + l15) * D_ + l4 * 8;
        const u16* krl = klo + base + (size_t)(j0 + l15) * D_ + l4 * 8;
        const bf16x8 bh0 = *(const bf16x8*)krh;
        const bf16x8 bl0 = *(const bf16x8*)krl;
        const bf16x8 bh1 = *(const bf16x8*)(krh + 32);
        const bf16x8 bl1 = *(const bf16x8*)(krl + 32);
        f32x4 acc = {0.f, 0.f, 0.f, 0.f};
        acc = MFMA(ah0, bh0, acc);
        acc = MFMA(ah0, bl0, acc);
        acc = MFMA(al0, bh0, acc);
        acc = MFMA(ah1, bh1, acc);
        acc = MFMA(ah1, bl1, acc);
        acc = MFMA(al1, bh1, acc);
        if (l4 < 2) {                      // rows 0..7 real; 8..15 duplicates
            const int j = j0 + l15;
            #pragma unroll
            for (int r = 0; r < 4; ++r) {
                const int mq = l4 * 4 + r;
                float s = acc[r];
                if (causal && j > q0 + mq) s = -INFINITY;
                sE[EIDX(mq, j)] = s;
                rm[r] = fmaxf(rm[r], s);
            }
        }
    }

    // ---- per-row block max ----
    #pragma unroll
    for (int r = 0; r < 4; ++r) {
        float v = rm[r];
        v = fmaxf(v, __shfl_xor(v, 1, 64));
        v = fmaxf(v, __shfl_xor(v, 2, 64));
        v = fmaxf(v, __shfl_xor(v, 4, 64));
        v = fmaxf(v, __shfl_xor(v, 8, 64));
        rm[r] = v;
    }
    if ((lane & 15) == 0 && l4 < 2) {
        #pragma unroll
        for (int r = 0; r < 4; ++r) sMaxP[w * QB + l4 * 4 + r] = rm[r];
    }
    __syncthreads();
    if (tid < QB) {
        sM[tid] = fmaxf(fmaxf(sMaxP[tid], sMaxP[QB + tid]),
                        fmaxf(sMaxP[2 * QB + tid], sMaxP[3 * QB + tid]));
    }
    __syncthreads();

    // ---- e = exp((s-m)/8) in place; zero-fill [jWritten, jPV) ----
    float m8[QB];
    #pragma unroll
    for (int r = 0; r < QB; ++r) m8[r] = sM[r];
    float ls[QB];
    #pragma unroll
    for (int r = 0; r < QB; ++r) ls[r] = 0.f;
    for (int j0q = tid * 4; j0q < jPV; j0q += NT * 4) {
        if (j0q < jWritten) {
            #pragma unroll
            for (int r = 0; r < QB; ++r) {
                f32x4 sv = *(const f32x4*)&sE[EIDX(r, j0q)];
                f32x4 e;
                e.x = __expf((sv.x - m8[r]) * 0.125f);
                e.y = __expf((sv.y - m8[r]) * 0.125f);
                e.z = __expf((sv.z - m8[r]) * 0.125f);
                e.w = __expf((sv.w - m8[r]) * 0.125f);
                *(f32x4*)&sE[EIDX(r, j0q)] = e;
                ls[r] += (e.x + e.y) + (e.z + e.w);
            }
        } else {
            const f32x4 z = {0.f, 0.f, 0.f, 0.f};
            #pragma unroll
            for (int r = 0; r < QB; ++r) *(f32x4*)&sE[EIDX(r, j0q)] = z;
        }
    }
    #pragma unroll
    for (int r = 0; r < QB; ++r) ls[r] = wred_sum(ls[r]);
    if (lane == 0) {
        #pragma unroll
        for (int r = 0; r < QB; ++r) sSumP[w * QB + r] = ls[r];
    }
    __syncthreads();
    if (tid < QB) {
        const float t0 = (sSumP[tid] + sSumP[QB + tid]) +
                         (sSumP[2 * QB + tid] + sSumP[3 * QB + tid]);
        sInv[tid] = 1.f / t0;
    }
    __syncthreads();

    // ---- attention rows: p = e*inv; nt stores ----
    {
        float inv8[QB];
        #pragma unroll
        for (int r = 0; r < QB; ++r) inv8[r] = sInv[r];
        const size_t arow = ((size_t)bh * S_ + q0) * S_;
        for (int j0a = tid * 4; j0a < S_; j0a += NT * 4) {
            const bool live = (j0a < jWritten);
            #pragma unroll
            for (int r = 0; r < QB; ++r) {
                f32x4 p = {0.f, 0.f, 0.f, 0.f};
                if (live) {
                    f32x4 v = *(const f32x4*)&sE[EIDX(r, j0a)];
                    p.x = v.x * inv8[r]; p.y = v.y * inv8[r];
                    p.z = v.z * inv8[r]; p.w = v.w * inv8[r];
                }
                __builtin_nontemporal_store(p, (f32x4*)(att + arow + (size_t)r * S_ + j0a));
            }
        }
    }

    // ---- PV: out tile 16q x 16d per wave (d0 = w*16); A=P (e from sE,
    // converted hi/lo in-reg), B=Vt hi/lo from ws; 3-term split; 2 accs ----
    const int d0 = w << 4;
    const int r8 = l15 & 7;
    const u16* vbh = vthi + base + (size_t)(d0 + l15) * S_;
    const u16* vbl = vtlo + base + (size_t)(d0 + l15) * S_;

#define PVSTEP(KS, ACC) {                                                    \
        const int jf = ((KS) << 5) + l4 * 8;                                 \
        const float* ep = &sE[EIDX(r8, jf)];                                 \
        f32x4 e0 = *(const f32x4*)ep;                                        \
        f32x4 e1 = *(const f32x4*)(ep + 4);                                  \
        bf16x8 ph, pl;                                                       \
        _Pragma("unroll")                                                    \
        for (int i = 0; i < 4; ++i) {                                        \
            u16 h0 = f2bf_rne(e0[i]);                                        \
            ph[i] = (short)h0;                                               \
            pl[i] = (short)f2bf_rne(e0[i] - bf2f(h0));                       \
            u16 h1 = f2bf_rne(e1[i]);                                        \
            ph[4 + i] = (short)h1;                                           \
            pl[4 + i] = (short)f2bf_rne(e1[i] - bf2f(h1));                   \
        }                                                                    \
        const bf16x8 vh = *(const bf16x8*)(vbh + jf);                        \
        const bf16x8 vl = *(const bf16x8*)(vbl + jf);                        \
        ACC = MFMA(ph, vh, ACC);                                             \
        ACC = MFMA(ph, vl, ACC);                                             \
        ACC = MFMA(pl, vh, ACC);                                             \
    }

    f32x4 acc0 = {0.f, 0.f, 0.f, 0.f};
    f32x4 acc1 = {0.f, 0.f, 0.f, 0.f};
    int ks = 0;
    for (; ks + 1 < Kc; ks += 2) { PVSTEP(ks, acc0) PVSTEP(ks + 1, acc1) }
    if (ks < Kc) PVSTEP(ks, acc0)
    const f32x4 accs = acc0 + acc1;
    if (l4 < 2) {
        #pragma unroll
        for (int r = 0; r < 4; ++r) {
            const int mq = l4 * 4 + r;
            out[((size_t)bh * S_ + q0 + mq) * D_ + d0 + l15] = accs[r] * sInv[mq];
        }
    }
#undef PVSTEP
}

// ---------------- fallback: round-5 VALU kernel (used if ws too small) ----------------
__global__ __launch_bounds__(NT)
void attn_tile8_kernel(const void* __restrict__ Qv, const void* __restrict__ Kv,
                       const void* __restrict__ Vv, const int* __restrict__ maskp,
                       float* __restrict__ out, float* __restrict__ att)
{
    const int tid = threadIdx.x;
    const int bid0 = blockIdx.x;
    const int bid  = (bid0 & 7) * 1024 + (bid0 >> 3);
    const int bh = bid >> 8;
    const int q0 = (bid & 255) << 3;
    const int causal = maskp[0];
    const int kmaxB = causal ? (q0 + QB - 1) : (S_ - 1);

    __shared__ float sS[QB * S_];
    __shared__ float sMaxP[4 * QB];
    __shared__ float sSumP[4 * QB];
    __shared__ float sInv[QB];

    const size_t base = (size_t)bh * S_ * D_;
    const int lane = tid & 63;
    const int wid  = tid >> 6;
    const bool isf32 = sniff_f32(Qv, lane);

    int km[QB];
    #pragma unroll
    for (int r = 0; r < QB; ++r) km[r] = causal ? (q0 + r) : (S_ - 1);
    float lm[QB];
    #pragma unroll
    for (int r = 0; r < QB; ++r) lm[r] = -INFINITY;

    if (isf32) {
        const float4* Q4u = reinterpret_cast<const float4*>((const float*)Qv + base + (size_t)q0 * D_);
        const float4* K4 = reinterpret_cast<const float4*>((const float*)Kv + base);
        for (int off = 0; off <= kmaxB; off += NT) {
            const int j = off + tid;
            if (j <= kmaxB) {
                const float4* kr = K4 + (size_t)j * 16;
                float4 kq[16];
                #pragma unroll
                for (int c = 0; c < 16; ++c) kq[c] = kr[c];
                float dd[QB];
                #pragma unroll
                for (int r = 0; r < QB; ++r) dd[r] = 0.f;
                #pragma unroll
                for (int c = 0; c < 16; ++c) {
                    #pragma unroll
                    for (int r = 0; r < QB; ++r) {
                        float4 a = Q4u[r * 16 + c];
                        dd[r] += a.x*kq[c].x + a.y*kq[c].y + a.z*kq[c].z + a.w*kq[c].w;
                    }
                }
                #pragma unroll
                for (int r = 0; r < QB; ++r) {
                    float s = (j <= km[r]) ? dd[r] : -INFINITY;
                    sS[r * S_ + j] = s;
                    lm[r] = fmaxf(lm[r], s);
                }
            }
        }
    } else {
        const u16* Qh = (const u16*)Qv + base + (size_t)q0 * D_;
        const u16* Kh = (const u16*)Kv + base;
        for (int off = 0; off <= kmaxB; off += NT) {
            const int j = off + tid;
            if (j <= kmaxB) {
                const u16* kr = Kh + (size_t)j * D_;
                float dd[QB];
                #pragma unroll
                for (int r = 0; r < QB; ++r) dd[r] = 0.f;
                #pragma unroll
                for (int c = 0; c < D_; ++c) {
                    float kc = bf2f(kr[c]);
                    #pragma unroll
                    for (int r = 0; r < QB; ++r) dd[r] += bf2f(Qh[r * D_ + c]) * kc;
                }
                #pragma unroll
                for (int r = 0; r < QB; ++r) {
                    float s = (j <= km[r]) ? dd[r] : -INFINITY;
                    sS[r * S_ + j] = s;
                    lm[r] = fmaxf(lm[r], s);
                }
            }
        }
    }

    #pragma unroll
    for (int r = 0; r < QB; ++r) lm[r] = wred_max(lm[r]);
    if (lane == 0) {
        #pragma unroll
        for (int r = 0; r < QB; ++r) sMaxP[wid * QB + r] = lm[r];
    }
    __syncthreads();
    float m[QB];
    #pragma unroll
    for (int r = 0; r < QB; ++r)
        m[r] = fmaxf(fmaxf(sMaxP[r], sMaxP[QB + r]), fmaxf(sMaxP[2*QB + r], sMaxP[3*QB + r]));

    float ls[QB];
    #pragma unroll
    for (int r = 0; r < QB; ++r) ls[r] = 0.f;
    for (int off = 0; off < S_; off += NT * 4) {
        const int j0e = off + tid * 4;
        if (j0e <= kmaxB) {
            #pragma unroll
            for (int r = 0; r < QB; ++r) {
                float4 sv = *reinterpret_cast<float4*>(sS + r * S_ + j0e);
                float e0 = __expf((sv.x - m[r]) * 0.125f);
                float e1 = __expf((sv.y - m[r]) * 0.125f);
                float e2 = __expf((sv.z - m[r]) * 0.125f);
                float e3 = __expf((sv.w - m[r]) * 0.125f);
                *reinterpret_cast<float4*>(sS + r * S_ + j0e) = make_float4(e0, e1, e2, e3);
                ls[r] += (e0 + e1) + (e2 + e3);
            }
        }
    }
    #pragma unroll
    for (int r = 0; r < QB; ++r) ls[r] = wred_sum(ls[r]);
    if (lane == 0) {
        #pragma unroll
        for (int r = 0; r < QB; ++r) sSumP[wid * QB + r] = ls[r];
    }
    __syncthreads();
    float inv[QB];
    #pragma unroll
    for (int r = 0; r < QB; ++r)
        inv[r] = 1.f / ((sSumP[r] + sSumP[QB + r]) + (sSumP[2*QB + r] + sSumP[3*QB + r]));
    if (tid == 0) {
        #pragma unroll
        for (int r = 0; r < QB; ++r) sInv[r] = inv[r];
    }

    {
        const size_t arow = ((size_t)bh * S_ + q0) * S_;
        for (int off = 0; off < S_; off += NT * 4) {
            const int j0a = off + tid * 4;
            const bool wr = (j0a <= kmaxB);
            #pragma unroll
            for (int r = 0; r < QB; ++r) {
                f32x4 p;
                if (wr) {
                    float4 v = *reinterpret_cast<const float4*>(sS + r * S_ + j0a);
                    p.x = v.x * inv[r]; p.y = v.y * inv[r];
                    p.z = v.z * inv[r]; p.w = v.w * inv[r];
                } else { p.x = 0.f; p.y = 0.f; p.z = 0.f; p.w = 0.f; }
                __builtin_nontemporal_store(p, reinterpret_cast<f32x4*>(att + arow + (size_t)r * S_ + j0a));
            }
        }
    }

    const int dq = tid & 15;
    const int jg = tid >> 4;
    float4 acc[QB];
    #pragma unroll
    for (int r = 0; r < QB; ++r) acc[r] = make_float4(0.f, 0.f, 0.f, 0.f);
    if (isf32) {
        const float4* V4 = reinterpret_cast<const float4*>((const float*)Vv + base);
        for (int j0p = 4 * jg; j0p <= kmaxB; j0p += 64) {
            float4 v0 = V4[(size_t)(j0p + 0) * 16 + dq];
            float4 v1 = V4[(size_t)(j0p + 1) * 16 + dq];
            float4 v2 = V4[(size_t)(j0p + 2) * 16 + dq];
            float4 v3 = V4[(size_t)(j0p + 3) * 16 + dq];
            #pragma unroll
            for (int r = 0; r < QB; ++r) {
                float4 p = *reinterpret_cast<const float4*>(sS + r * S_ + j0p);
                acc[r].x = fmaf(p.x, v0.x, acc[r].x); acc[r].y = fmaf(p.x, v0.y, acc[r].y);
                acc[r].z = fmaf(p.x, v0.z, acc[r].z); acc[r].w = fmaf(p.x, v0.w, acc[r].w);
                acc[r].x = fmaf(p.y, v1.x, acc[r].x); acc[r].y = fmaf(p.y, v1.y, acc[r].y);
                acc[r].z = fmaf(p.y, v1.z, acc[r].z); acc[r].w = fmaf(p.y, v1.w, acc[r].w);
                acc[r].x = fmaf(p.z, v2.x, acc[r].x); acc[r].y = fmaf(p.z, v2.y, acc[r].y);
                acc[r].z = fmaf(p.z, v2.z, acc[r].z); acc[r].w = fmaf(p.z, v2.w, acc[r].w);
                acc[r].x = fmaf(p.w, v3.x, acc[r].x); acc[r].y = fmaf(p.w, v3.y, acc[r].y);
                acc[r].z = fmaf(p.w, v3.z, acc[r].z); acc[r].w = fmaf(p.w, v3.w, acc[r].w);
            }
        }
    } else {
        const u16* Vh = (const u16*)Vv + base;
        for (int j0p = 4 * jg; j0p <= kmaxB; j0p += 64) {
            ushort4 h0 = reinterpret_cast<const ushort4*>(Vh + (size_t)(j0p + 0) * D_)[dq];
            ushort4 h1 = reinterpret_cast<const ushort4*>(Vh + (size_t)(j0p + 1) * D_)[dq];
            ushort4 h2 = reinterpret_cast<const ushort4*>(Vh + (size_t)(j0p + 2) * D_)[dq];
            ushort4 h3 = reinterpret_cast<const ushort4*>(Vh + (size_t)(j0p + 3) * D_)[dq];
            float4 v0 = make_float4(bf2f(h0.x), bf2f(h0.y), bf2f(h0.z), bf2f(h0.w));
            float4 v1 = make_float4(bf2f(h1.x), bf2f(h1.y), bf2f(h1.z), bf2f(h1.w));
            float4 v2 = make_float4(bf2f(h2.x), bf2f(h2.y), bf2f(h2.z), bf2f(h2.w));
            float4 v3 = make_float4(bf2f(h3.x), bf2f(h3.y), bf2f(h3.z), bf2f(h3.w));
            #pragma unroll
            for (int r = 0; r < QB; ++r) {
                float4 p = *reinterpret_cast<const float4*>(sS + r * S_ + j0p);
                acc[r].x = fmaf(p.x, v0.x, acc[r].x); acc[r].y = fmaf(p.x, v0.y, acc[r].y);
                acc[r].z = fmaf(p.x, v0.z, acc[r].z); acc[r].w = fmaf(p.x, v0.w, acc[r].w);
                acc[r].x = fmaf(p.y, v1.x, acc[r].x); acc[r].y = fmaf(p.y, v1.y, acc[r].y);
                acc[r].z = fmaf(p.y, v1.z, acc[r].z); acc[r].w = fmaf(p.y, v1.w, acc[r].w);
                acc[r].x = fmaf(p.z, v2.x, acc[r].x); acc[r].y = fmaf(p.z, v2.y, acc[r].y);
                acc[r].z = fmaf(p.z, v2.z, acc[r].z); acc[r].w = fmaf(p.z, v2.w, acc[r].w);
                acc[r].x = fmaf(p.w, v3.x, acc[r].x); acc[r].y = fmaf(p.w, v3.y, acc[r].y);
                acc[r].z = fmaf(p.w, v3.z, acc[r].z); acc[r].w = fmaf(p.w, v3.w, acc[r].w);
            }
        }
    }

    __syncthreads();
    float4* sPart4 = reinterpret_cast<float4*>(sS);
    #pragma unroll
    for (int r = 0; r < QB; ++r) sPart4[(r * 16 + jg) * 17 + dq] = acc[r];
    __syncthreads();
    {
        const float* spf = sS;
        for (int oo = tid; oo < QB * D_; oo += NT) {
            const int r = oo >> 6;
            const int d = oo & 63;
            float o = 0.f;
            #pragma unroll
            for (int g = 0; g < 16; ++g) o += spf[(r * 16 + g) * 68 + d];
            out[((size_t)bh * S_ + q0 + r) * D_ + d] = o * sInv[r];
        }
    }
}

extern "C" void kernel_launch(void* const* d_in, const int* in_sizes, int n_in,
                              void* d_out, int out_size, void* d_ws, size_t ws_size,
                              hipStream_t stream) {
    const void* Q = d_in[0];
    const void* K = d_in[1];
    const void* V = d_in[2];
    const int* mask = (const int*)d_in[3];

    float* out = (float*)d_out;                              // B*H*S*D floats
    float* att = out + (size_t)B_ * H_ * S_ * D_;            // B*H*S*S floats

    if (d_ws != nullptr && ws_size >= WS_NEEDED) {
        u16* W = (u16*)d_ws;
        u16* qhi = W;
        u16* qlo = W + 1ull * ELEMS;
        u16* khi = W + 2ull * ELEMS;
        u16* klo = W + 3ull * ELEMS;
        u16* vthi = W + 4ull * ELEMS;
        u16* vtlo = W + 5ull * ELEMS;
        conv_kernel<<<B_ * H_ * (S_ / 64), 256, 0, stream>>>(Q, K, V, qhi, qlo, khi, klo, vthi, vtlo);
        attn_mfma_kernel<<<(B_ * H_ * S_) / QB, NT, 0, stream>>>(qhi, qlo, khi, klo, vthi, vtlo,
                                                                 mask, out, att);
    } else {
        attn_tile8_kernel<<<(B_ * H_ * S_) / QB, NT, 0, stream>>>(Q, K, V, mask, out, att);
    }
}